// Round 4
// baseline (224.584 us; speedup 1.0000x reference)
//
#include <hip/hip_runtime.h>
#include <hip/hip_bf16.h>

// EfficientAttention: x(4,256,64,64) -> qkv(192ch) -> attn(N=4096,c=64) -> proj(256ch)
// k_prep: qkv weights fp32->bf16 frag layout (QSC folded into Q rows/bias).
// k_qkv (R4): 512 blocks x 32-token tiles (was 256 x 64), 6 waves. 2 blocks/CU
//         -> shorter serial phases + cross-block overlap. Frag outputs:
//   Qf/Kf: [b][chunk32][kk(4)][lane(64)][8]
//   Vf   : [b][chunk32][ct(2)ks(2)][lane(64)][j(8)] = producer reg order
// k_attn (R4): 16 waves (1024 thr), barrier-free, direct global->reg K/V.
//         R0-R3 established: barriers lockstep-stall (R2), 2 waves/SIMD can't
//         hide serial L2 latency (R1), compiler defeats manual reg pipelines
//         (R3, VGPR stayed 128). Untested quadrant = many waves + no barriers:
//         4 waves/SIMD of independent serial streams cover ~300cyc L2 latency
//         with ~300cyc compute each (m114 wave-level overlap). Each wave keeps
//         BOTH q-subtiles + a k-sixteenth (8 iters) so K/V L2 traffic stays
//         256MB and VGPR ~124 < 128 cap for 4 waves/SIMD.

#define N_TOK 4096
#define CDIM  64
#define DIM   256
#define NBAT  4

typedef __attribute__((ext_vector_type(8)))  short          short8;
typedef __attribute__((ext_vector_type(8)))  unsigned short ushort8_t;
typedef __attribute__((ext_vector_type(4)))  unsigned short ushort4_t;
typedef __attribute__((ext_vector_type(4)))  unsigned int   uint4_t;
typedef __attribute__((ext_vector_type(4)))  float          float4_t;
typedef __attribute__((ext_vector_type(16))) float          float16_t;

#if __has_builtin(__builtin_amdgcn_exp2f)
#define QSC  0.18033688011112042f   /* 0.125 * log2(e): p = exp2(s) */
#define PEXP(x) __builtin_amdgcn_exp2f(x)
#else
#define QSC  0.125f
#define PEXP(x) __expf(x)
#endif

__device__ __forceinline__ unsigned short f2bf(float f) {
  unsigned int u = __builtin_bit_cast(unsigned int, f);
  u += 0x7fffu + ((u >> 16) & 1u);            // RNE
  return (unsigned short)(u >> 16);
}

// packed f32x2 -> bf16x2 dword (v_cvt_pk_bf16_f32 on gfx950, RNE)
__device__ __forceinline__ unsigned int pkcv(float a, float b) {
  __hip_bfloat162 h = __float22bfloat162_rn(make_float2(a, b));
  unsigned int r; __builtin_memcpy(&r, &h, 4); return r;
}

__device__ __forceinline__ short8 ld8(const unsigned short* p) {
  return __builtin_bit_cast(short8, *(const ushort8_t*)p);
}

__device__ __forceinline__ short8 pack8f(float4_t a, float4_t b) {
  uint4_t u;
  u[0] = pkcv(a[0], a[1]); u[1] = pkcv(a[2], a[3]);
  u[2] = pkcv(b[0], b[1]); u[3] = pkcv(b[2], b[3]);
  return __builtin_bit_cast(short8, u);
}

__device__ __forceinline__ float16_t z16() {
  float16_t r;
#pragma unroll
  for (int i = 0; i < 16; ++i) r[i] = 0.0f;
  return r;
}

#define MFMA(a, b, c) __builtin_amdgcn_mfma_f32_32x32x16_bf16((a), (b), (c), 0, 0, 0)

// ws layout (u16 units)
#define QOFF  0                // 4*128*4*512 = 1048576 each
#define KOFF  1048576
#define VOFF  2097152
#define WQOFF 3145728          // 192*256
#define BSOFF 3194880          // scaled qkv bias, fp32 (192)

// ---------------------------------------------------------------------------
// k_prep: grid 24 x 256. qkv_w -> bf16 frag layout (Q rows scaled by QSC);
// bias -> fp32 with Q-scale fold.
// ---------------------------------------------------------------------------
__global__ void k_prep(const float* __restrict__ qw, const float* __restrict__ qb,
                       unsigned short* __restrict__ wqs, float* __restrict__ bs)
{
  const int g = blockIdx.x * 256 + threadIdx.x;   // 0..6143
  {
    const int lane = g & 63, grp = g >> 6;
    const int w6 = grp >> 4, kk = grp & 15;
    const int o = w6 * 32 + (lane & 31);
    const int c = kk * 16 + (lane >> 5) * 8;
    const float sc = (o < 64) ? QSC : 1.0f;
    const float* src = qw + o * 256 + c;
    ushort8_t u;
#pragma unroll
    for (int j = 0; j < 8; ++j) u[j] = f2bf(src[j] * sc);
    *(ushort8_t*)(wqs + g * 8) = u;
  }
  if (g < 48) {
    float4_t f = *(const float4_t*)(qb + g * 4);
    float4_t o;
#pragma unroll
    for (int j = 0; j < 4; ++j) o[j] = f[j] * ((g * 4 + j) < 64 ? QSC : 1.0f);
    *(float4_t*)(bs + g * 4) = o;
  }
}

// ---------------------------------------------------------------------------
// k_qkv: grid 512 x 384 thr (6 waves). Block: 32-token tile (one chunk),
// all 192 o. Wave w = o-tile (32 o x 32 n, 16 MFMA).
// Waves 0-3 (Q,K): C[o rows][n cols]; waves 4-5 (V): swapped operands.
// ---------------------------------------------------------------------------
#define RS 132   // Xl row stride in dwords

__global__ __launch_bounds__(384, 2) void k_qkv(
    const float* __restrict__ x, const unsigned short* __restrict__ wqs,
    const float* __restrict__ bs, unsigned short* __restrict__ Qf,
    unsigned short* __restrict__ Kf, unsigned short* __restrict__ Vf)
{
  __shared__ unsigned int Xl[32 * RS];
  const int id = blockIdx.x;
  const int b  = (id >> 1) & 3;
  const int ch = (id & 1) | ((id >> 3) << 1);   // 0..127 (32-token chunk)
  const int t  = threadIdx.x;
  const int n0g = ch * 32;

  if (t < 256) {
    const int n0  = (t & 7) * 4;                 // token group within tile
    const int cpb = t >> 3;                      // 0..31
#pragma unroll
    for (int p = 0; p < 4; ++p) {
      const int cp = cpb + 32 * p, c = cp * 2;
      const float* xb = x + (((size_t)(b * DIM + c)) << 12) + n0g + n0;
      float4_t a = *(const float4_t*)xb;
      float4_t d = *(const float4_t*)(xb + 4096);
#pragma unroll
      for (int j = 0; j < 4; ++j)
        Xl[(n0 + j) * RS + cp] = pkcv(a[j], d[j]);
    }
  }
  __syncthreads();

  const int w = t >> 6, lane = t & 63, l31 = lane & 31, lh = lane >> 5;
  const unsigned short* wrow = wqs + ((w * 16) << 9) + lane * 8;
  const unsigned int*   xr0  = &Xl[l31 * RS + lh * 4];

  float16_t a0 = z16();
  if (w < 4) {
#pragma unroll
    for (int kk = 0; kk < 16; ++kk) {
      short8 wf = ld8(wrow + (kk << 9));
      short8 x0 = __builtin_bit_cast(short8, *(const uint4_t*)(xr0 + kk * 8));
      a0 = MFMA(wf, x0, a0);                     // C[o rows][n cols]
    }
  } else {
#pragma unroll
    for (int kk = 0; kk < 16; ++kk) {
      short8 wf = ld8(wrow + (kk << 9));
      short8 x0 = __builtin_bit_cast(short8, *(const uint4_t*)(xr0 + kk * 8));
      a0 = MFMA(x0, wf, a0);                     // C[token rows][c cols]
    }
  }

  if (w < 4) {
    unsigned short* dst = (w < 2) ? Qf : Kf;
    const int w2 = w & 1;                        // c64-half of Q or K
#pragma unroll
    for (int p = 0; p < 4; ++p) {
      const int o = w * 32 + p * 8 + lh * 4;     // global qkv channel
      float4_t bv = *(const float4_t*)(bs + o);
      ushort4_t pk4;
#pragma unroll
      for (int q = 0; q < 4; ++q) pk4[q] = f2bf(a0[p * 4 + q] + bv[q]);
      const int kkt = w2 * 2 + (p >> 1);
      *(ushort4_t*)(dst + ((((b * 128 + ch) * 4 + kkt) << 9)
                           + (l31 + 32 * (p & 1)) * 8 + lh * 4)) = pk4;
    }
  } else {
    const int ct = w - 4;                        // c-group of V
    const float bvs = bs[128 + ct * 32 + l31];
#pragma unroll
    for (int ks = 0; ks < 2; ++ks) {
      ushort8_t pk8;
#pragma unroll
      for (int j = 0; j < 8; ++j) pk8[j] = f2bf(a0[ks * 8 + j] + bvs);
      *(ushort8_t*)(Vf + ((((b * 128 + ch) * 4 + ct * 2 + ks) << 9)
                          + lane * 8)) = pk8;
    }
  }
}

// ---------------------------------------------------------------------------
// k_attn: grid 256 x 1024 thr (16 waves). Block: 64 q-rows.
// Wave wv owns key-chunks {16*it+wv} (it=0..7), BOTH 32-q subtiles (K/V regs
// reused 2x -> L2 traffic unchanged vs 8-wave). Direct global->VGPR loads,
// zero main-loop barriers: 4 waves/SIMD of independent streams hide L2
// latency. Partials combined via LDS atomics; fused proj epilogue.
// ---------------------------------------------------------------------------
#define OS   68    // Oacc row stride (fp32)
#define OLS  72    // Ol row stride (bf16)
#define NACC (64 * OS + 64)

__global__ __launch_bounds__(1024, 4) void k_attn(
    const unsigned short* __restrict__ Qf, const unsigned short* __restrict__ Kf,
    const unsigned short* __restrict__ Vf, const float* __restrict__ pw,
    const float* __restrict__ pb, float* __restrict__ out)
{
  __shared__ float Oacc[NACC];                             // O[n][c] + den tail
  __shared__ __align__(16) unsigned short Ol[64 * OLS];

  const int id = blockIdx.x;
  const int b  = (id >> 1) & 3;
  const int nt = (id & 1) | ((id >> 3) << 1);        // 0..63
  const int t  = threadIdx.x;
  const int wv = t >> 6, lane = t & 63, l31 = lane & 31, lh = lane >> 5;

  for (int i = t; i < NACC; i += 1024) Oacc[i] = 0.0f;

  // Q frags for BOTH n-subtiles (QSC pre-folded)
  short8 qf0[4], qf1[4];
#pragma unroll
  for (int kk = 0; kk < 4; ++kk) {
    qf0[kk] = ld8(Qf + (((b * 128 + nt * 2 + 0) * 4 + kk) << 9) + lane * 8);
    qf1[kk] = ld8(Qf + (((b * 128 + nt * 2 + 1) * 4 + kk) << 9) + lane * 8);
  }

  // wave's chunk base: chunk wv of batch b; advance 16 chunks (1<<15 u16)/iter
  const unsigned short* kb = Kf + (((size_t)(b * 128 + wv)) << 11) + lane * 8;
  const unsigned short* vb = Vf + (((size_t)(b * 128 + wv)) << 11) + lane * 8;

  float16_t oc00 = z16(), oc01 = z16();   // nsub 0, ct 0/1
  float16_t oc10 = z16(), oc11 = z16();   // nsub 1, ct 0/1
  float den0 = 0.0f, den1 = 0.0f;

  __syncthreads();   // Oacc zeroed before epilogue atomics

  for (int it = 0; it < 8; ++it) {
    const size_t o = ((size_t)it) << 15;
    short8 k0 = ld8(kb + o),        k1 = ld8(kb + o + 512);
    short8 k2 = ld8(kb + o + 1024), k3 = ld8(kb + o + 1536);
    short8 v0 = ld8(vb + o),        v1 = ld8(vb + o + 512);
    short8 v2 = ld8(vb + o + 1024), v3 = ld8(vb + o + 1536);

    // S^T tiles: lane col n = l31, row m = (e&3)+8*(e>>2)+4*lh
    float16_t s0 = z16(), s1 = z16();
    s0 = MFMA(k0, qf0[0], s0); s0 = MFMA(k1, qf0[1], s0);
    s0 = MFMA(k2, qf0[2], s0); s0 = MFMA(k3, qf0[3], s0);
    s1 = MFMA(k0, qf1[0], s1); s1 = MFMA(k1, qf1[1], s1);
    s1 = MFMA(k2, qf1[2], s1); s1 = MFMA(k3, qf1[3], s1);

    {
      float p[16];
#pragma unroll
      for (int e = 0; e < 16; ++e) p[e] = PEXP(s0[e]);
      float d0 = (p[0] + p[1]) + (p[2] + p[3]);
      float d1 = (p[4] + p[5]) + (p[6] + p[7]);
      float d2 = (p[8] + p[9]) + (p[10] + p[11]);
      float d3 = (p[12] + p[13]) + (p[14] + p[15]);
      den0 += (d0 + d1) + (d2 + d3);

      uint4_t w0, w1;
#pragma unroll
      for (int j = 0; j < 4; ++j) {
        w0[j] = pkcv(p[2 * j], p[2 * j + 1]);
        w1[j] = pkcv(p[8 + 2 * j], p[9 + 2 * j]);
      }
      short8 pf0 = __builtin_bit_cast(short8, w0);   // m 0..15 of chunk
      short8 pf1 = __builtin_bit_cast(short8, w1);   // m 16..31
      oc00 = MFMA(pf0, v0, oc00);
      oc00 = MFMA(pf1, v1, oc00);
      oc01 = MFMA(pf0, v2, oc01);
      oc01 = MFMA(pf1, v3, oc01);
    }
    {
      float p[16];
#pragma unroll
      for (int e = 0; e < 16; ++e) p[e] = PEXP(s1[e]);
      float d0 = (p[0] + p[1]) + (p[2] + p[3]);
      float d1 = (p[4] + p[5]) + (p[6] + p[7]);
      float d2 = (p[8] + p[9]) + (p[10] + p[11]);
      float d3 = (p[12] + p[13]) + (p[14] + p[15]);
      den1 += (d0 + d1) + (d2 + d3);

      uint4_t w0, w1;
#pragma unroll
      for (int j = 0; j < 4; ++j) {
        w0[j] = pkcv(p[2 * j], p[2 * j + 1]);
        w1[j] = pkcv(p[8 + 2 * j], p[9 + 2 * j]);
      }
      short8 pf0 = __builtin_bit_cast(short8, w0);
      short8 pf1 = __builtin_bit_cast(short8, w1);
      oc10 = MFMA(pf0, v0, oc10);
      oc10 = MFMA(pf1, v1, oc10);
      oc11 = MFMA(pf0, v2, oc11);
      oc11 = MFMA(pf1, v3, oc11);
    }
  }

  den0 += __shfl_xor(den0, 32);   // combine lane halves (m coverage)
  den1 += __shfl_xor(den1, 32);

  // combine 16-way k-chunk partials: O[n][c] (+ den) via LDS atomics
#pragma unroll
  for (int ct = 0; ct < 2; ++ct) {
    const float16_t& oa = ct ? oc01 : oc00;
    const int cc = ct * 32 + l31;
#pragma unroll
    for (int e = 0; e < 16; ++e) {
      const int nr = (e & 3) + 8 * (e >> 2) + 4 * lh;
      atomicAdd(&Oacc[nr * OS + cc], oa[e]);
    }
  }
#pragma unroll
  for (int ct = 0; ct < 2; ++ct) {
    const float16_t& oa = ct ? oc11 : oc10;
    const int cc = ct * 32 + l31;
#pragma unroll
    for (int e = 0; e < 16; ++e) {
      const int nr = 32 + (e & 3) + 8 * (e >> 2) + 4 * lh;
      atomicAdd(&Oacc[nr * OS + cc], oa[e]);
    }
  }
  if (lane < 32) {
    atomicAdd(&Oacc[64 * OS + l31],      den0);
    atomicAdd(&Oacc[64 * OS + 32 + l31], den1);
  }
  __syncthreads();

  // normalize + cast -> Ol[n][c] bf16 (8 thr/row, first 512 threads)
  if (t < 512) {
    const int nloc = t >> 3, c8 = (t & 7) * 8;
    float4_t s0 = *(float4_t*)&Oacc[nloc * OS + c8];
    float4_t s1 = *(float4_t*)&Oacc[nloc * OS + c8 + 4];
    const float r = 1.0f / Oacc[64 * OS + nloc];
    uint4_t o4;
    o4[0] = pkcv(s0[0] * r, s0[1] * r);
    o4[1] = pkcv(s0[2] * r, s0[3] * r);
    o4[2] = pkcv(s1[0] * r, s1[1] * r);
    o4[3] = pkcv(s1[2] * r, s1[3] * r);
    *(uint4_t*)&Ol[nloc * OLS + c8] = o4;
  }
  __syncthreads();

  // fused proj: wave wv -> o-tile wv>>1 (32 o), n-subtile wv&1; raw fp32 W
  {
    const int ot = wv >> 1, nsub = wv & 1;
    float16_t f0 = z16();
    const float* pwrow = pw + (ot * 32 + l31) * 64 + lh * 8;
#pragma unroll
    for (int kk = 0; kk < 4; ++kk) {
      float4_t wa = *(const float4_t*)(pwrow + kk * 16);
      float4_t wb = *(const float4_t*)(pwrow + kk * 16 + 4);
      short8 af = pack8f(wa, wb);
      short8 bfr = ld8(&Ol[(nsub * 32 + l31) * OLS + kk * 16 + lh * 8]);
      f0 = MFMA(af, bfr, f0);
    }
    const int n0 = nt * 64;
#pragma unroll
    for (int e = 0; e < 16; ++e) {
      const int o = ot * 32 + (e & 3) + 8 * (e >> 2) + 4 * lh;
      const float bv = pb[o];
      out[((b * 256 + o) << 12) + n0 + nsub * 32 + l31] = f0[e] + bv;
    }
  }
}

extern "C" void kernel_launch(void* const* d_in, const int* in_sizes, int n_in,
                              void* d_out, int out_size, void* d_ws, size_t ws_size,
                              hipStream_t stream) {
  const float* x      = (const float*)d_in[0];
  const float* qkv_w  = (const float*)d_in[1];
  const float* qkv_b  = (const float*)d_in[2];
  const float* proj_w = (const float*)d_in[3];
  const float* proj_b = (const float*)d_in[4];
  float* out = (float*)d_out;

  unsigned short* ws  = (unsigned short*)d_ws;
  unsigned short* qf  = ws + QOFF;
  unsigned short* kf  = ws + KOFF;
  unsigned short* vf  = ws + VOFF;
  unsigned short* wqs = ws + WQOFF;
  float*          bs  = (float*)(ws + BSOFF);

  k_prep<<<24, 256, 0, stream>>>(qkv_w, qkv_b, wqs, bs);
  k_qkv<<<512, 384, 0, stream>>>(x, wqs, bs, qf, kf, vf);
  k_attn<<<256, 1024, 0, stream>>>(qf, kf, vf, proj_w, proj_b, out);
}

// Round 5
// 132.759 us; speedup vs baseline: 1.6917x; 1.6917x over previous
//
#include <hip/hip_runtime.h>
#include <hip/hip_bf16.h>

// EfficientAttention: x(4,256,64,64) -> qkv(192ch) -> attn(N=4096,c=64) -> proj(256ch)
// k_prep: qkv weights fp32->bf16 frag layout (QSC folded into Q rows/bias).
// k_qkv (R5): 256 blocks x 64-token tiles, 768 thr (12 waves, 3/SIMD). Each
//         wave = ONE (o-tile, 32-token chunk) task, 16 MFMA. All 16 weight
//         frags hoisted to regs (wf[16], ~64 VGPR) and issued BEFORE the
//         barrier so L2 latency overlaps x staging. Phase 1 spread over 512
//         threads (4-deep chains, was 8 over 256). launch_bounds(768,3):
//         cap 170 VGPR, state ~110 -> no spill (R4 lesson: forced caps below
//         live state = scratch catastrophe, FETCH 5.4->140MB).
//   Qf/Kf: [b][chunk32][kk(4)][lane(64)][8]
//   Vf   : [b][chunk32][ct(2)ks(2)][lane(64)][j(8)] = producer reg order
// k_attn: R0 verbatim (best of 5 structural variants: 57.2us). 256-token K/V
//         tiles (128KB LDS dbuf via global_load_lds), 16 barriers, full tile
//         of compute covering each DMA drain.

#define N_TOK 4096
#define CDIM  64
#define DIM   256
#define NBAT  4

typedef __attribute__((ext_vector_type(8)))  short          short8;
typedef __attribute__((ext_vector_type(8)))  unsigned short ushort8_t;
typedef __attribute__((ext_vector_type(4)))  unsigned short ushort4_t;
typedef __attribute__((ext_vector_type(4)))  unsigned int   uint4_t;
typedef __attribute__((ext_vector_type(4)))  float          float4_t;
typedef __attribute__((ext_vector_type(16))) float          float16_t;

#if __has_builtin(__builtin_amdgcn_exp2f)
#define QSC  0.18033688011112042f   /* 0.125 * log2(e): p = exp2(s) */
#define PEXP(x) __builtin_amdgcn_exp2f(x)
#else
#define QSC  0.125f
#define PEXP(x) __expf(x)
#endif

__device__ __forceinline__ unsigned short f2bf(float f) {
  unsigned int u = __builtin_bit_cast(unsigned int, f);
  u += 0x7fffu + ((u >> 16) & 1u);            // RNE
  return (unsigned short)(u >> 16);
}

// packed f32x2 -> bf16x2 dword (v_cvt_pk_bf16_f32 on gfx950, RNE)
__device__ __forceinline__ unsigned int pkcv(float a, float b) {
  __hip_bfloat162 h = __float22bfloat162_rn(make_float2(a, b));
  unsigned int r; __builtin_memcpy(&r, &h, 4); return r;
}

__device__ __forceinline__ short8 ld8(const unsigned short* p) {
  return __builtin_bit_cast(short8, *(const ushort8_t*)p);
}

__device__ __forceinline__ short8 pack8f(float4_t a, float4_t b) {
  uint4_t u;
  u[0] = pkcv(a[0], a[1]); u[1] = pkcv(a[2], a[3]);
  u[2] = pkcv(b[0], b[1]); u[3] = pkcv(b[2], b[3]);
  return __builtin_bit_cast(short8, u);
}

__device__ __forceinline__ float16_t z16() {
  float16_t r;
#pragma unroll
  for (int i = 0; i < 16; ++i) r[i] = 0.0f;
  return r;
}

// async global->LDS DMA: 64 lanes x 16B; LDS dst = wave-uniform base (+lane*16 by HW)
typedef __attribute__((address_space(1))) const void* gvp;
typedef __attribute__((address_space(3))) void*       lvp;
__device__ __forceinline__ void dma16(const unsigned short* g, unsigned short* l) {
  __builtin_amdgcn_global_load_lds((gvp)g, (lvp)l, 16, 0, 0);
}

#define MFMA(a, b, c) __builtin_amdgcn_mfma_f32_32x32x16_bf16((a), (b), (c), 0, 0, 0)

// ws layout (u16 units)
#define QOFF  0                // 4*128*4*512 = 1048576 each
#define KOFF  1048576
#define VOFF  2097152
#define WQOFF 3145728          // 192*256
#define BSOFF 3194880          // scaled qkv bias, fp32 (192)

// ---------------------------------------------------------------------------
// k_prep: grid 24 x 256. qkv_w -> bf16 frag layout (Q rows scaled by QSC);
// bias -> fp32 with Q-scale fold.
// ---------------------------------------------------------------------------
__global__ void k_prep(const float* __restrict__ qw, const float* __restrict__ qb,
                       unsigned short* __restrict__ wqs, float* __restrict__ bs)
{
  const int g = blockIdx.x * 256 + threadIdx.x;   // 0..6143
  {
    const int lane = g & 63, grp = g >> 6;
    const int w6 = grp >> 4, kk = grp & 15;
    const int o = w6 * 32 + (lane & 31);
    const int c = kk * 16 + (lane >> 5) * 8;
    const float sc = (o < 64) ? QSC : 1.0f;
    const float* src = qw + o * 256 + c;
    ushort8_t u;
#pragma unroll
    for (int j = 0; j < 8; ++j) u[j] = f2bf(src[j] * sc);
    *(ushort8_t*)(wqs + g * 8) = u;
  }
  if (g < 48) {
    float4_t f = *(const float4_t*)(qb + g * 4);
    float4_t o;
#pragma unroll
    for (int j = 0; j < 4; ++j) o[j] = f[j] * ((g * 4 + j) < 64 ? QSC : 1.0f);
    *(float4_t*)(bs + g * 4) = o;
  }
}

// ---------------------------------------------------------------------------
// k_qkv: grid 256 x 768 thr (12 waves). Block: 64-token tile, all 192 o.
// Wave w: o-tile (w>>1), chunk (w&1). Weight frags hoisted to wf[16] before
// the barrier (overlaps x staging). Waves 0-7 (Q,K): C[o rows][n cols];
// waves 8-11 (V): swapped operands -> C[token rows][c cols].
// ---------------------------------------------------------------------------
#define RS 132   // Xl row stride in dwords

__global__ __launch_bounds__(768, 3) void k_qkv(
    const float* __restrict__ x, const unsigned short* __restrict__ wqs,
    const float* __restrict__ bs, unsigned short* __restrict__ Qf,
    unsigned short* __restrict__ Kf, unsigned short* __restrict__ Vf)
{
  __shared__ unsigned int Xl[64 * RS];
  const int id = blockIdx.x;
  const int b  = (id >> 1) & 3;
  const int nt = (id & 1) | ((id >> 3) << 1);   // 0..63 (64-token tile)
  const int t  = threadIdx.x;
  const int n0g = nt * 64;

  if (t < 512) {
    const int n0  = (t & 15) * 4;
    const int cpb = t >> 4;                      // 0..31
#pragma unroll
    for (int p = 0; p < 4; ++p) {
      const int cp = cpb + 32 * p, c = cp * 2;
      const float* xb = x + (((size_t)(b * DIM + c)) << 12) + n0g + n0;
      float4_t a = *(const float4_t*)xb;
      float4_t d = *(const float4_t*)(xb + 4096);
#pragma unroll
      for (int j = 0; j < 4; ++j)
        Xl[(n0 + j) * RS + cp] = pkcv(a[j], d[j]);
    }
  }

  const int w = t >> 6, lane = t & 63, l31 = lane & 31, lh = lane >> 5;
  const int ot = w >> 1, sub = w & 1;
  const int ch = nt * 2 + sub;                   // global 32-token chunk

  // hoist all 16 weight frags (independent L2 loads, issued pre-barrier)
  const unsigned short* wrow = wqs + ((ot * 16) << 9) + lane * 8;
  short8 wf[16];
#pragma unroll
  for (int kk = 0; kk < 16; ++kk) wf[kk] = ld8(wrow + (kk << 9));

  __syncthreads();

  const unsigned int* xr = &Xl[(sub * 32 + l31) * RS + lh * 4];

  float16_t a0 = z16();
  if (ot < 4) {
#pragma unroll
    for (int kk = 0; kk < 16; ++kk) {
      short8 xf = __builtin_bit_cast(short8, *(const uint4_t*)(xr + kk * 8));
      a0 = MFMA(wf[kk], xf, a0);                 // C[o rows][n cols]
    }
  } else {
#pragma unroll
    for (int kk = 0; kk < 16; ++kk) {
      short8 xf = __builtin_bit_cast(short8, *(const uint4_t*)(xr + kk * 8));
      a0 = MFMA(xf, wf[kk], a0);                 // C[token rows][c cols]
    }
  }

  if (ot < 4) {
    unsigned short* dst = (ot < 2) ? Qf : Kf;
    const int w2 = ot & 1;                       // c64-half of Q or K
#pragma unroll
    for (int p = 0; p < 4; ++p) {
      const int o = ot * 32 + p * 8 + lh * 4;    // global qkv channel
      float4_t bv = *(const float4_t*)(bs + o);
      ushort4_t pk4;
#pragma unroll
      for (int q = 0; q < 4; ++q) pk4[q] = f2bf(a0[p * 4 + q] + bv[q]);
      const int kkt = w2 * 2 + (p >> 1);
      *(ushort4_t*)(dst + ((((b * 128 + ch) * 4 + kkt) << 9)
                           + (l31 + 32 * (p & 1)) * 8 + lh * 4)) = pk4;
    }
  } else {
    const int ct = ot - 4;                       // c-group of V
    const float bvs = bs[128 + ct * 32 + l31];
#pragma unroll
    for (int ks = 0; ks < 2; ++ks) {
      ushort8_t pk8;
#pragma unroll
      for (int j = 0; j < 8; ++j) pk8[j] = f2bf(a0[ks * 8 + j] + bvs);
      *(ushort8_t*)(Vf + ((((b * 128 + ch) * 4 + ct * 2 + ks) << 9)
                          + lane * 8)) = pk8;
    }
  }
}

// ---------------------------------------------------------------------------
// k_attn: grid 256 x 512 thr (8 waves). Block: 64 q-rows. (R0 verbatim)
// Outer: 16 tiles of 256 tokens (8 chunks), LDS dbuf via global_load_lds.
// Staging: waves 0-3 K chunks {2w,2w+1}; waves 4-7 V likewise (8KB/wave/tile).
// Compute: wave wv -> m-chunks {2mq, 2mq+1} of the tile, n-subtile (wv&1).
// One barrier per tile (16 total) — DMA drain covered by a full tile.
// ---------------------------------------------------------------------------
#define OS   68    // Oacc row stride (fp32)
#define OLS  72    // Ol row stride (bf16)
#define NACC (64 * OS + 64)

__global__ __launch_bounds__(512, 1) void k_attn(
    const unsigned short* __restrict__ Qf, const unsigned short* __restrict__ Kf,
    const unsigned short* __restrict__ Vf, const float* __restrict__ pw,
    const float* __restrict__ pb, float* __restrict__ out)
{
  __shared__ __align__(16) unsigned short KV[2][2][16384]; // [buf][K|V][8ch*2048]
  __shared__ float Oacc[NACC];                             // O[n][c] + den tail
  __shared__ __align__(16) unsigned short Ol[64 * OLS];

  const int id = blockIdx.x;
  const int b  = (id >> 1) & 3;
  const int nt = (id & 1) | ((id >> 3) << 1);        // 0..63
  const int t  = threadIdx.x;
  const int wv = t >> 6, lane = t & 63, l31 = lane & 31, lh = lane >> 5;
  const int mq = wv >> 1, nsub = wv & 1;

  for (int i = t; i < NACC; i += 512) Oacc[i] = 0.0f;

  // staging role: wave stages 2 chunks of K (wv<4) or V (wv>=4)
  const int kvsel = wv >> 2;
  const int wq2   = (wv & 3) * 2;                    // first staged chunk in tile
  const unsigned short* sg = ((kvsel == 0) ? Kf : Vf)
                             + (((size_t)(b * 128 + wq2)) << 11) + lane * 8;

  // Q frags (QSC pre-folded)
  short8 qf[4];
#pragma unroll
  for (int kk = 0; kk < 4; ++kk)
    qf[kk] = ld8(Qf + (((b * 128 + nt * 2 + nsub) * 4 + kk) << 9) + lane * 8);

  // stage tile 0 into buf 0
#pragma unroll
  for (int c2 = 0; c2 < 2; ++c2)
#pragma unroll
    for (int kk = 0; kk < 4; ++kk)
      dma16(sg + (c2 << 11) + (kk << 9),
            &KV[0][kvsel][((wq2 + c2) << 11) + (kk << 9)]);

  float16_t oc0 = z16(), oc1 = z16();
  float den = 0.0f;

  __syncthreads();   // Oacc zeroed + tile 0 resident

  for (int t4 = 0; t4 < 16; ++t4) {
    const int cur = t4 & 1;

    // stage tile t4+1 (drained at the NEXT barrier, a full tile later)
    if (t4 < 15) {
      const unsigned short* g = sg + (((size_t)(t4 + 1)) << 14);
#pragma unroll
      for (int c2 = 0; c2 < 2; ++c2)
#pragma unroll
        for (int kk = 0; kk < 4; ++kk)
          dma16(g + (c2 << 11) + (kk << 9),
                &KV[cur ^ 1][kvsel][((wq2 + c2) << 11) + (kk << 9)]);
    }

#pragma unroll
    for (int cc = 0; cc < 2; ++cc) {
      const int ch = mq * 2 + cc;                    // my m-chunk in tile
      const unsigned short* kl = &KV[cur][0][ch << 11];
      const unsigned short* vl = &KV[cur][1][ch << 11];

      short8 kf0 = ld8(kl + lane * 8);
      short8 kf1 = ld8(kl + 512 + lane * 8);
      short8 kf2 = ld8(kl + 1024 + lane * 8);
      short8 kf3 = ld8(kl + 1536 + lane * 8);

      // S^T tile: lane col n = l31, row m = (e&3)+8*(e>>2)+4*lh
      float16_t s = z16();
      s = MFMA(kf0, qf[0], s);
      s = MFMA(kf1, qf[1], s);
      s = MFMA(kf2, qf[2], s);
      s = MFMA(kf3, qf[3], s);

      float p[16];
#pragma unroll
      for (int e = 0; e < 16; ++e) p[e] = PEXP(s[e]);
      {
        float d0 = (p[0] + p[1]) + (p[2] + p[3]);
        float d1 = (p[4] + p[5]) + (p[6] + p[7]);
        float d2 = (p[8] + p[9]) + (p[10] + p[11]);
        float d3 = (p[12] + p[13]) + (p[14] + p[15]);
        den += (d0 + d1) + (d2 + d3);
      }

      // S regs ARE the O-MFMA A-operand (V k-slots pre-permuted at production)
      uint4_t w0, w1;
#pragma unroll
      for (int j = 0; j < 4; ++j) {
        w0[j] = pkcv(p[2 * j], p[2 * j + 1]);
        w1[j] = pkcv(p[8 + 2 * j], p[9 + 2 * j]);
      }
      short8 pf0 = __builtin_bit_cast(short8, w0);   // m 0..15 of chunk
      short8 pf1 = __builtin_bit_cast(short8, w1);   // m 16..31

      short8 vf0 = ld8(vl + lane * 8);               // ct0 ks0
      short8 vf1 = ld8(vl + 512 + lane * 8);         // ct0 ks1
      short8 vf2 = ld8(vl + 1024 + lane * 8);        // ct1 ks0
      short8 vf3 = ld8(vl + 1536 + lane * 8);        // ct1 ks1

      oc0 = MFMA(pf0, vf0, oc0);
      oc0 = MFMA(pf1, vf1, oc0);
      oc1 = MFMA(pf0, vf2, oc1);
      oc1 = MFMA(pf1, vf3, oc1);
    }

    __syncthreads();   // drains next-tile DMA + frees cur buffer
  }

  den += __shfl_xor(den, 32);   // combine lane halves (m coverage)

  // combine m-chunk partials: O[n][c] (+ den) via LDS atomics
#pragma unroll
  for (int ct = 0; ct < 2; ++ct) {
    const float16_t& oa = ct ? oc1 : oc0;
    const int cc = ct * 32 + l31;
#pragma unroll
    for (int e = 0; e < 16; ++e) {
      const int nr = nsub * 32 + (e & 3) + 8 * (e >> 2) + 4 * lh;
      atomicAdd(&Oacc[nr * OS + cc], oa[e]);
    }
  }
  if (lane < 32) atomicAdd(&Oacc[64 * OS + nsub * 32 + l31], den);
  __syncthreads();

  // normalize + cast -> Ol[n][c] bf16 (8 thr/row)
  {
    const int nloc = t >> 3, c8 = (t & 7) * 8;
    float4_t s0 = *(float4_t*)&Oacc[nloc * OS + c8];
    float4_t s1 = *(float4_t*)&Oacc[nloc * OS + c8 + 4];
    const float r = 1.0f / Oacc[64 * OS + nloc];
    uint4_t o4;
    o4[0] = pkcv(s0[0] * r, s0[1] * r);
    o4[1] = pkcv(s0[2] * r, s0[3] * r);
    o4[2] = pkcv(s1[0] * r, s1[1] * r);
    o4[3] = pkcv(s1[2] * r, s1[3] * r);
    *(uint4_t*)&Ol[nloc * OLS + c8] = o4;
  }
  __syncthreads();

  // fused proj: wave wv -> o-tile wv (32 o), both n-subtiles; raw fp32 W
  float16_t f0 = z16(), f1 = z16();
  const float* pwrow = pw + (wv * 32 + l31) * 64 + lh * 8;
#pragma unroll
  for (int kk = 0; kk < 4; ++kk) {
    float4_t wa = *(const float4_t*)(pwrow + kk * 16);
    float4_t wb = *(const float4_t*)(pwrow + kk * 16 + 4);
    short8 af = pack8f(wa, wb);
    short8 b0 = ld8(&Ol[l31 * OLS + kk * 16 + lh * 8]);
    short8 b1 = ld8(&Ol[(32 + l31) * OLS + kk * 16 + lh * 8]);
    f0 = MFMA(af, b0, f0);
    f1 = MFMA(af, b1, f1);
  }
  const int n0 = nt * 64;
#pragma unroll
  for (int e = 0; e < 16; ++e) {
    const int o = wv * 32 + (e & 3) + 8 * (e >> 2) + 4 * lh;
    const float bv = pb[o];
    out[((b * 256 + o) << 12) + n0 + l31]      = f0[e] + bv;
    out[((b * 256 + o) << 12) + n0 + 32 + l31] = f1[e] + bv;
  }
}

extern "C" void kernel_launch(void* const* d_in, const int* in_sizes, int n_in,
                              void* d_out, int out_size, void* d_ws, size_t ws_size,
                              hipStream_t stream) {
  const float* x      = (const float*)d_in[0];
  const float* qkv_w  = (const float*)d_in[1];
  const float* qkv_b  = (const float*)d_in[2];
  const float* proj_w = (const float*)d_in[3];
  const float* proj_b = (const float*)d_in[4];
  float* out = (float*)d_out;

  unsigned short* ws  = (unsigned short*)d_ws;
  unsigned short* qf  = ws + QOFF;
  unsigned short* kf  = ws + KOFF;
  unsigned short* vf  = ws + VOFF;
  unsigned short* wqs = ws + WQOFF;
  float*          bs  = (float*)(ws + BSOFF);

  k_prep<<<24, 256, 0, stream>>>(qkv_w, qkv_b, wqs, bs);
  k_qkv<<<256, 768, 0, stream>>>(x, wqs, bs, qf, kf, vf);
  k_attn<<<256, 512, 0, stream>>>(qf, kf, vf, proj_w, proj_b, out);
}

// Round 6
// 130.965 us; speedup vs baseline: 1.7148x; 1.0137x over previous
//
#include <hip/hip_runtime.h>
#include <hip/hip_bf16.h>

// EfficientAttention: x(4,256,64,64) -> qkv(192ch) -> attn(N=4096,c=64) -> proj(256ch)
// k_prep: qkv weights fp32->bf16 frag layout (QSC folded into Q rows/bias).
// k_qkv (R5): 256 blocks x 64-token tiles, 768 thr (12 waves). Wave = ONE
//         (o-tile, chunk) task; 16 weight frags hoisted pre-barrier.
//   Qf/Kf: [b][chunk32][kk(4)][lane(64)][8]
//   Vf   : [b][chunk32][ct(2)ks(2)][lane(64)][j(8)] = producer reg order
// k_attn (R6): K-only LDS staging (V read direct global->reg: V frags are
//         L2-resident and consumed right after the ~200cyc exp/pack phase,
//         which covers the L2 latency -- guide m169: V-staging of L2-fit data
//         is pure overhead). Freed LDS doubles K-tiles to 512 tokens
//         (16 chunks, 2x64KB dbuf): 8 barriers (was 16), DMA bytes/block
//         halved (1MB->512KB), compute per barrier doubled (4 chunks/wave).
//         R0-R5 established the per-tile DMA+full-drain cycle (~8.5k cyc/tile
//         vs ~500cyc compute) as the gate; this attacks both factors.

#define N_TOK 4096
#define CDIM  64
#define DIM   256
#define NBAT  4

typedef __attribute__((ext_vector_type(8)))  short          short8;
typedef __attribute__((ext_vector_type(8)))  unsigned short ushort8_t;
typedef __attribute__((ext_vector_type(4)))  unsigned short ushort4_t;
typedef __attribute__((ext_vector_type(4)))  unsigned int   uint4_t;
typedef __attribute__((ext_vector_type(4)))  float          float4_t;
typedef __attribute__((ext_vector_type(16))) float          float16_t;

#if __has_builtin(__builtin_amdgcn_exp2f)
#define QSC  0.18033688011112042f   /* 0.125 * log2(e): p = exp2(s) */
#define PEXP(x) __builtin_amdgcn_exp2f(x)
#else
#define QSC  0.125f
#define PEXP(x) __expf(x)
#endif

__device__ __forceinline__ unsigned short f2bf(float f) {
  unsigned int u = __builtin_bit_cast(unsigned int, f);
  u += 0x7fffu + ((u >> 16) & 1u);            // RNE
  return (unsigned short)(u >> 16);
}

// packed f32x2 -> bf16x2 dword (v_cvt_pk_bf16_f32 on gfx950, RNE)
__device__ __forceinline__ unsigned int pkcv(float a, float b) {
  __hip_bfloat162 h = __float22bfloat162_rn(make_float2(a, b));
  unsigned int r; __builtin_memcpy(&r, &h, 4); return r;
}

__device__ __forceinline__ short8 ld8(const unsigned short* p) {
  return __builtin_bit_cast(short8, *(const ushort8_t*)p);
}

__device__ __forceinline__ short8 pack8f(float4_t a, float4_t b) {
  uint4_t u;
  u[0] = pkcv(a[0], a[1]); u[1] = pkcv(a[2], a[3]);
  u[2] = pkcv(b[0], b[1]); u[3] = pkcv(b[2], b[3]);
  return __builtin_bit_cast(short8, u);
}

__device__ __forceinline__ float16_t z16() {
  float16_t r;
#pragma unroll
  for (int i = 0; i < 16; ++i) r[i] = 0.0f;
  return r;
}

// async global->LDS DMA: 64 lanes x 16B; LDS dst = wave-uniform base (+lane*16 by HW)
typedef __attribute__((address_space(1))) const void* gvp;
typedef __attribute__((address_space(3))) void*       lvp;
__device__ __forceinline__ void dma16(const unsigned short* g, unsigned short* l) {
  __builtin_amdgcn_global_load_lds((gvp)g, (lvp)l, 16, 0, 0);
}

#define MFMA(a, b, c) __builtin_amdgcn_mfma_f32_32x32x16_bf16((a), (b), (c), 0, 0, 0)

// ws layout (u16 units)
#define QOFF  0                // 4*128*4*512 = 1048576 each
#define KOFF  1048576
#define VOFF  2097152
#define WQOFF 3145728          // 192*256
#define BSOFF 3194880          // scaled qkv bias, fp32 (192)

// ---------------------------------------------------------------------------
// k_prep: grid 24 x 256. qkv_w -> bf16 frag layout (Q rows scaled by QSC);
// bias -> fp32 with Q-scale fold.
// ---------------------------------------------------------------------------
__global__ void k_prep(const float* __restrict__ qw, const float* __restrict__ qb,
                       unsigned short* __restrict__ wqs, float* __restrict__ bs)
{
  const int g = blockIdx.x * 256 + threadIdx.x;   // 0..6143
  {
    const int lane = g & 63, grp = g >> 6;
    const int w6 = grp >> 4, kk = grp & 15;
    const int o = w6 * 32 + (lane & 31);
    const int c = kk * 16 + (lane >> 5) * 8;
    const float sc = (o < 64) ? QSC : 1.0f;
    const float* src = qw + o * 256 + c;
    ushort8_t u;
#pragma unroll
    for (int j = 0; j < 8; ++j) u[j] = f2bf(src[j] * sc);
    *(ushort8_t*)(wqs + g * 8) = u;
  }
  if (g < 48) {
    float4_t f = *(const float4_t*)(qb + g * 4);
    float4_t o;
#pragma unroll
    for (int j = 0; j < 4; ++j) o[j] = f[j] * ((g * 4 + j) < 64 ? QSC : 1.0f);
    *(float4_t*)(bs + g * 4) = o;
  }
}

// ---------------------------------------------------------------------------
// k_qkv: grid 256 x 768 thr (12 waves). Block: 64-token tile, all 192 o.
// Wave w: o-tile (w>>1), chunk (w&1). Weight frags hoisted to wf[16] before
// the barrier (overlaps x staging). Waves 0-7 (Q,K): C[o rows][n cols];
// waves 8-11 (V): swapped operands -> C[token rows][c cols].
// ---------------------------------------------------------------------------
#define RS 132   // Xl row stride in dwords

__global__ __launch_bounds__(768, 3) void k_qkv(
    const float* __restrict__ x, const unsigned short* __restrict__ wqs,
    const float* __restrict__ bs, unsigned short* __restrict__ Qf,
    unsigned short* __restrict__ Kf, unsigned short* __restrict__ Vf)
{
  __shared__ unsigned int Xl[64 * RS];
  const int id = blockIdx.x;
  const int b  = (id >> 1) & 3;
  const int nt = (id & 1) | ((id >> 3) << 1);   // 0..63 (64-token tile)
  const int t  = threadIdx.x;
  const int n0g = nt * 64;

  if (t < 512) {
    const int n0  = (t & 15) * 4;
    const int cpb = t >> 4;                      // 0..31
#pragma unroll
    for (int p = 0; p < 4; ++p) {
      const int cp = cpb + 32 * p, c = cp * 2;
      const float* xb = x + (((size_t)(b * DIM + c)) << 12) + n0g + n0;
      float4_t a = *(const float4_t*)xb;
      float4_t d = *(const float4_t*)(xb + 4096);
#pragma unroll
      for (int j = 0; j < 4; ++j)
        Xl[(n0 + j) * RS + cp] = pkcv(a[j], d[j]);
    }
  }

  const int w = t >> 6, lane = t & 63, l31 = lane & 31, lh = lane >> 5;
  const int ot = w >> 1, sub = w & 1;
  const int ch = nt * 2 + sub;                   // global 32-token chunk

  // hoist all 16 weight frags (independent L2 loads, issued pre-barrier)
  const unsigned short* wrow = wqs + ((ot * 16) << 9) + lane * 8;
  short8 wf[16];
#pragma unroll
  for (int kk = 0; kk < 16; ++kk) wf[kk] = ld8(wrow + (kk << 9));

  __syncthreads();

  const unsigned int* xr = &Xl[(sub * 32 + l31) * RS + lh * 4];

  float16_t a0 = z16();
  if (ot < 4) {
#pragma unroll
    for (int kk = 0; kk < 16; ++kk) {
      short8 xf = __builtin_bit_cast(short8, *(const uint4_t*)(xr + kk * 8));
      a0 = MFMA(wf[kk], xf, a0);                 // C[o rows][n cols]
    }
  } else {
#pragma unroll
    for (int kk = 0; kk < 16; ++kk) {
      short8 xf = __builtin_bit_cast(short8, *(const uint4_t*)(xr + kk * 8));
      a0 = MFMA(xf, wf[kk], a0);                 // C[token rows][c cols]
    }
  }

  if (ot < 4) {
    unsigned short* dst = (ot < 2) ? Qf : Kf;
    const int w2 = ot & 1;                       // c64-half of Q or K
#pragma unroll
    for (int p = 0; p < 4; ++p) {
      const int o = ot * 32 + p * 8 + lh * 4;    // global qkv channel
      float4_t bv = *(const float4_t*)(bs + o);
      ushort4_t pk4;
#pragma unroll
      for (int q = 0; q < 4; ++q) pk4[q] = f2bf(a0[p * 4 + q] + bv[q]);
      const int kkt = w2 * 2 + (p >> 1);
      *(ushort4_t*)(dst + ((((b * 128 + ch) * 4 + kkt) << 9)
                           + (l31 + 32 * (p & 1)) * 8 + lh * 4)) = pk4;
    }
  } else {
    const int ct = ot - 4;                       // c-group of V
    const float bvs = bs[128 + ct * 32 + l31];
#pragma unroll
    for (int ks = 0; ks < 2; ++ks) {
      ushort8_t pk8;
#pragma unroll
      for (int j = 0; j < 8; ++j) pk8[j] = f2bf(a0[ks * 8 + j] + bvs);
      *(ushort8_t*)(Vf + ((((b * 128 + ch) * 4 + ct * 2 + ks) << 9)
                          + lane * 8)) = pk8;
    }
  }
}

// ---------------------------------------------------------------------------
// k_attn: grid 256 x 512 thr (8 waves). Block: 64 q-rows.
// Outer: 8 tiles of 512 tokens (16 chunks). K staged in LDS (2x64KB dbuf via
// global_load_lds, each wave stages chunks {2wv,2wv+1}); V read DIRECT
// global->reg per chunk (exp/pack phase covers the L2 latency).
// Compute: wave wv -> m-chunks {4mq..4mq+3} of the tile, n-subtile (wv&1).
// One barrier per tile (8 total).
// ---------------------------------------------------------------------------
#define OS   68    // Oacc row stride (fp32)
#define OLS  72    // Ol row stride (bf16)
#define NACC (64 * OS + 64)

__global__ __launch_bounds__(512, 1) void k_attn(
    const unsigned short* __restrict__ Qf, const unsigned short* __restrict__ Kf,
    const unsigned short* __restrict__ Vf, const float* __restrict__ pw,
    const float* __restrict__ pb, float* __restrict__ out)
{
  __shared__ __align__(16) unsigned short Kl[2][32768];    // [buf][16ch*2048]
  __shared__ float Oacc[NACC];                             // O[n][c] + den tail
  __shared__ __align__(16) unsigned short Ol[64 * OLS];

  const int id = blockIdx.x;
  const int b  = (id >> 1) & 3;
  const int nt = (id & 1) | ((id >> 3) << 1);        // 0..63
  const int t  = threadIdx.x;
  const int wv = t >> 6, lane = t & 63, l31 = lane & 31, lh = lane >> 5;
  const int mq = wv >> 1, nsub = wv & 1;

  for (int i = t; i < NACC; i += 512) Oacc[i] = 0.0f;

  // staging role: wave stages K chunks {2wv, 2wv+1} of each 16-chunk tile
  const int wq2 = wv * 2;
  const unsigned short* sg = Kf + (((size_t)(b * 128 + wq2)) << 11) + lane * 8;

  // Q frags (QSC pre-folded)
  short8 qf[4];
#pragma unroll
  for (int kk = 0; kk < 4; ++kk)
    qf[kk] = ld8(Qf + (((b * 128 + nt * 2 + nsub) * 4 + kk) << 9) + lane * 8);

  // V base for this batch (chunk index advances over tiles)
  const unsigned short* vbase = Vf + (((size_t)(b * 128)) << 11) + lane * 8;

  // stage tile 0 into buf 0
#pragma unroll
  for (int c2 = 0; c2 < 2; ++c2)
#pragma unroll
    for (int kk = 0; kk < 4; ++kk)
      dma16(sg + (c2 << 11) + (kk << 9),
            &Kl[0][((wq2 + c2) << 11) + (kk << 9)]);

  float16_t oc0 = z16(), oc1 = z16();
  float den = 0.0f;

  __syncthreads();   // Oacc zeroed + tile 0 resident

  for (int t8 = 0; t8 < 8; ++t8) {
    const int cur = t8 & 1;

    // stage tile t8+1 (drained at the NEXT barrier, a full tile later)
    if (t8 < 7) {
      const unsigned short* g = sg + (((size_t)(t8 + 1)) << 15);
#pragma unroll
      for (int c2 = 0; c2 < 2; ++c2)
#pragma unroll
        for (int kk = 0; kk < 4; ++kk)
          dma16(g + (c2 << 11) + (kk << 9),
                &Kl[cur ^ 1][((wq2 + c2) << 11) + (kk << 9)]);
    }

#pragma unroll
    for (int cc = 0; cc < 4; ++cc) {
      const int ch = mq * 4 + cc;                    // my m-chunk in tile
      const unsigned short* kl = &Kl[cur][ch << 11];

      short8 kf0 = ld8(kl + lane * 8);
      short8 kf1 = ld8(kl + 512 + lane * 8);
      short8 kf2 = ld8(kl + 1024 + lane * 8);
      short8 kf3 = ld8(kl + 1536 + lane * 8);

      // S^T tile: lane col n = l31, row m = (e&3)+8*(e>>2)+4*lh
      float16_t s = z16();
      s = MFMA(kf0, qf[0], s);
      s = MFMA(kf1, qf[1], s);
      s = MFMA(kf2, qf[2], s);
      s = MFMA(kf3, qf[3], s);

      float p[16];
#pragma unroll
      for (int e = 0; e < 16; ++e) p[e] = PEXP(s[e]);
      {
        float d0 = (p[0] + p[1]) + (p[2] + p[3]);
        float d1 = (p[4] + p[5]) + (p[6] + p[7]);
        float d2 = (p[8] + p[9]) + (p[10] + p[11]);
        float d3 = (p[12] + p[13]) + (p[14] + p[15]);
        den += (d0 + d1) + (d2 + d3);
      }

      // S regs ARE the O-MFMA A-operand (V k-slots pre-permuted at production)
      uint4_t w0, w1;
#pragma unroll
      for (int j = 0; j < 4; ++j) {
        w0[j] = pkcv(p[2 * j], p[2 * j + 1]);
        w1[j] = pkcv(p[8 + 2 * j], p[9 + 2 * j]);
      }
      short8 pf0 = __builtin_bit_cast(short8, w0);   // m 0..15 of chunk
      short8 pf1 = __builtin_bit_cast(short8, w1);   // m 16..31

      // V direct from global (L2-resident; exp/pack above covers latency)
      const unsigned short* vl = vbase + (((size_t)(t8 * 16 + ch)) << 11);
      short8 vf0 = ld8(vl);                          // ct0 ks0
      short8 vf1 = ld8(vl + 512);                    // ct0 ks1
      short8 vf2 = ld8(vl + 1024);                   // ct1 ks0
      short8 vf3 = ld8(vl + 1536);                   // ct1 ks1

      oc0 = MFMA(pf0, vf0, oc0);
      oc0 = MFMA(pf1, vf1, oc0);
      oc1 = MFMA(pf0, vf2, oc1);
      oc1 = MFMA(pf1, vf3, oc1);
    }

    __syncthreads();   // drains next-tile DMA + frees cur buffer
  }

  den += __shfl_xor(den, 32);   // combine lane halves (m coverage)

  // combine m-chunk partials: O[n][c] (+ den) via LDS atomics
#pragma unroll
  for (int ct = 0; ct < 2; ++ct) {
    const float16_t& oa = ct ? oc1 : oc0;
    const int cc = ct * 32 + l31;
#pragma unroll
    for (int e = 0; e < 16; ++e) {
      const int nr = nsub * 32 + (e & 3) + 8 * (e >> 2) + 4 * lh;
      atomicAdd(&Oacc[nr * OS + cc], oa[e]);
    }
  }
  if (lane < 32) atomicAdd(&Oacc[64 * OS + nsub * 32 + l31], den);
  __syncthreads();

  // normalize + cast -> Ol[n][c] bf16 (8 thr/row)
  {
    const int nloc = t >> 3, c8 = (t & 7) * 8;
    float4_t s0 = *(float4_t*)&Oacc[nloc * OS + c8];
    float4_t s1 = *(float4_t*)&Oacc[nloc * OS + c8 + 4];
    const float r = 1.0f / Oacc[64 * OS + nloc];
    uint4_t o4;
    o4[0] = pkcv(s0[0] * r, s0[1] * r);
    o4[1] = pkcv(s0[2] * r, s0[3] * r);
    o4[2] = pkcv(s1[0] * r, s1[1] * r);
    o4[3] = pkcv(s1[2] * r, s1[3] * r);
    *(uint4_t*)&Ol[nloc * OLS + c8] = o4;
  }
  __syncthreads();

  // fused proj: wave wv -> o-tile wv (32 o), both n-subtiles; raw fp32 W
  float16_t f0 = z16(), f1 = z16();
  const float* pwrow = pw + (wv * 32 + l31) * 64 + lh * 8;
#pragma unroll
  for (int kk = 0; kk < 4; ++kk) {
    float4_t wa = *(const float4_t*)(pwrow + kk * 16);
    float4_t wb = *(const float4_t*)(pwrow + kk * 16 + 4);
    short8 af = pack8f(wa, wb);
    short8 b0 = ld8(&Ol[l31 * OLS + kk * 16 + lh * 8]);
    short8 b1 = ld8(&Ol[(32 + l31) * OLS + kk * 16 + lh * 8]);
    f0 = MFMA(af, b0, f0);
    f1 = MFMA(af, b1, f1);
  }
  const int n0 = nt * 64;
#pragma unroll
  for (int e = 0; e < 16; ++e) {
    const int o = wv * 32 + (e & 3) + 8 * (e >> 2) + 4 * lh;
    const float bv = pb[o];
    out[((b * 256 + o) << 12) + n0 + l31]      = f0[e] + bv;
    out[((b * 256 + o) << 12) + n0 + 32 + l31] = f1[e] + bv;
  }
}

extern "C" void kernel_launch(void* const* d_in, const int* in_sizes, int n_in,
                              void* d_out, int out_size, void* d_ws, size_t ws_size,
                              hipStream_t stream) {
  const float* x      = (const float*)d_in[0];
  const float* qkv_w  = (const float*)d_in[1];
  const float* qkv_b  = (const float*)d_in[2];
  const float* proj_w = (const float*)d_in[3];
  const float* proj_b = (const float*)d_in[4];
  float* out = (float*)d_out;

  unsigned short* ws  = (unsigned short*)d_ws;
  unsigned short* qf  = ws + QOFF;
  unsigned short* kf  = ws + KOFF;
  unsigned short* vf  = ws + VOFF;
  unsigned short* wqs = ws + WQOFF;
  float*          bs  = (float*)(ws + BSOFF);

  k_prep<<<24, 256, 0, stream>>>(qkv_w, qkv_b, wqs, bs);
  k_qkv<<<256, 768, 0, stream>>>(x, wqs, bs, qf, kf, vf);
  k_attn<<<256, 512, 0, stream>>>(qf, kf, vf, proj_w, proj_b, out);
}